// Round 9
// baseline (480.352 us; speedup 1.0000x reference)
//
#include <hip/hip_runtime.h>
#include <cstdint>
#include <cstddef>

#define HDIM 256
#define DIN 128
#define EPSV 1e-5f
#define SCHUNK 1024

typedef __attribute__((ext_vector_type(8))) short short8;   // 8 bf16 = 4 VGPRs
typedef __attribute__((ext_vector_type(4))) float f32x4;    // MFMA acc

__device__ __forceinline__ float bf2f(unsigned int u16) {
  union { unsigned int i; float f; } v; v.i = u16 << 16; return v.f;
}
__device__ __forceinline__ unsigned short f2bf(float f) {
  union { float f; unsigned int i; } v; v.f = f;
  unsigned int u = v.i;
  return (unsigned short)((u + 0x7fffu + ((u >> 16) & 1u)) >> 16);
}
__device__ __forceinline__ float4 ldbf4(const unsigned short* p) {
  uint2 v = *(const uint2*)p;
  return make_float4(bf2f(v.x & 0xffffu), bf2f(v.x >> 16),
                     bf2f(v.y & 0xffffu), bf2f(v.y >> 16));
}
__device__ __forceinline__ void stbf4(unsigned short* p, float a, float b, float c, float d) {
  uint2 o;
  o.x = (unsigned int)f2bf(a) | ((unsigned int)f2bf(b) << 16);
  o.y = (unsigned int)f2bf(c) | ((unsigned int)f2bf(d) << 16);
  *(uint2*)p = o;
}
#define ACC8(u) do { \
    acc[0] += bf2f((u).x & 0xffffu); acc[1] += bf2f((u).x >> 16); \
    acc[2] += bf2f((u).y & 0xffffu); acc[3] += bf2f((u).y >> 16); \
    acc[4] += bf2f((u).z & 0xffffu); acc[5] += bf2f((u).z >> 16); \
    acc[6] += bf2f((u).w & 0xffffu); acc[7] += bf2f((u).w >> 16); } while (0)

// ---------------- CSR build ----------------
__global__ __launch_bounds__(256) void hist_k(const int* __restrict__ col, int* deg, int e) {
  int i = blockIdx.x * 256 + threadIdx.x;
  if (i < e) atomicAdd(&deg[col[i]], 1);
}

__global__ __launch_bounds__(256) void scanA_k(const int* __restrict__ deg,
                                               int* __restrict__ row_ptr,
                                               int* __restrict__ blockSums,
                                               float* __restrict__ dis, int n) {
  __shared__ int waveSums[4];
  const int tid = threadIdx.x, lane = tid & 63, w = tid >> 6;
  const int base = blockIdx.x * SCHUNK + tid * 4;
  int v0 = 0, v1 = 0, v2 = 0, v3 = 0;
  if (base + 0 < n) v0 = deg[base + 0];
  if (base + 1 < n) v1 = deg[base + 1];
  if (base + 2 < n) v2 = deg[base + 2];
  if (base + 3 < n) v3 = deg[base + 3];
  if (base + 0 < n) dis[base + 0] = rsqrtf((float)(v0 + 1));
  if (base + 1 < n) dis[base + 1] = rsqrtf((float)(v1 + 1));
  if (base + 2 < n) dis[base + 2] = rsqrtf((float)(v2 + 1));
  if (base + 3 < n) dis[base + 3] = rsqrtf((float)(v3 + 1));
  int tsum = v0 + v1 + v2 + v3;
  int inc = tsum;
#pragma unroll
  for (int off = 1; off < 64; off <<= 1) {
    int t = __shfl_up(inc, off);
    if (lane >= off) inc += t;
  }
  if (lane == 63) waveSums[w] = inc;
  __syncthreads();
  int woff = 0;
#pragma unroll
  for (int k = 0; k < 4; ++k) woff += (k < w) ? waveSums[k] : 0;
  int excl = woff + inc - tsum;
  if (base + 0 < n) row_ptr[base + 0] = excl;
  if (base + 1 < n) row_ptr[base + 1] = excl + v0;
  if (base + 2 < n) row_ptr[base + 2] = excl + v0 + v1;
  if (base + 3 < n) row_ptr[base + 3] = excl + v0 + v1 + v2;
  if (tid == 255) blockSums[blockIdx.x] = woff + inc;
}

// scanC: per-block computes its prefix over <=64 block sums, adds to row_ptr
__global__ __launch_bounds__(256) void scanC_k(int* __restrict__ row_ptr,
                                               const int* __restrict__ bsums,
                                               int n, int e, int nbs) {
  __shared__ int s_add;
  if (threadIdx.x < 64) {
    int v = (threadIdx.x < nbs && threadIdx.x < blockIdx.x) ? bsums[threadIdx.x] : 0;
#pragma unroll
    for (int off = 1; off < 64; off <<= 1) v += __shfl_xor(v, off);
    if (threadIdx.x == 0) s_add = v;
  }
  __syncthreads();
  const int add = s_add;
  const int base = blockIdx.x * SCHUNK + threadIdx.x * 4;
#pragma unroll
  for (int k = 0; k < 4; ++k)
    if (base + k < n) row_ptr[base + k] += add;
  if (blockIdx.x == 0 && threadIdx.x == 0) row_ptr[n] = e;
}

__global__ __launch_bounds__(256) void fill_k(const int* __restrict__ row,
                                              const int* __restrict__ col,
                                              const int* __restrict__ row_ptr,
                                              int* cur, int* srcs, int e) {
  int i = blockIdx.x * 256 + threadIdx.x;
  if (i < e) {
    int c = col[i];
    int p = row_ptr[c] + atomicAdd(&cur[c], 1);
    srcs[p] = row[i];
  }
}

// ---------------- prep: pack 4 weights + cast scaled x ----------------
__device__ __forceinline__ void packW(const float* __restrict__ W,
                                      unsigned short* __restrict__ out,
                                      int idx, int C) {
  int j = idx & 7, lane = (idx >> 3) & 63, rest = idx >> 9;
  int NSUB = C >> 4;
  int ns = rest % NSUB, kb = rest / NSUB;
  int k = kb * 32 + (lane >> 4) * 8 + j;
  int c = ns * 16 + (lane & 15);
  out[idx] = f2bf(W[(size_t)k * C + c]);
}

__global__ __launch_bounds__(256) void prep_k(
    const float* __restrict__ W1, const float* __restrict__ W2,
    const float* __restrict__ W3, const float* __restrict__ Wf1,
    const float* __restrict__ x, const float* __restrict__ dis,
    unsigned short* __restrict__ W1p, unsigned short* __restrict__ W2p,
    unsigned short* __restrict__ W3p, unsigned short* __restrict__ Wf1p,
    unsigned short* __restrict__ xs, int nx) {
  int idx = blockIdx.x * 256 + threadIdx.x;
  const int s0 = DIN * HDIM, s1 = s0 + HDIM * HDIM, s2 = s1 + HDIM * HDIM,
            s3 = s2 + HDIM * 128;
  if (idx < s0) packW(W1, W1p, idx, HDIM);
  else if (idx < s1) packW(W2, W2p, idx - s0, HDIM);
  else if (idx < s2) packW(W3, W3p, idx - s1, HDIM);
  else if (idx < s3) packW(Wf1, Wf1p, idx - s2, 128);
  else {
    int o = idx - s3;
    if (o < nx) xs[o] = f2bf(x[o] * dis[o >> 7]);   // row = o/128
  }
}

// ============ FUSED: gather(64 rows -> LDS) + GEMM + bias + LN + ReLU + res ====
// 512 threads = 8 waves. Phase 1: each wave gathers 8 target rows into LDS
// (bf16, row stride K+8 shorts -> 2-way bank aliasing only). Phase 2: MFMA
// 64x256 GEMM from LDS A-frags + global weights; per-row LN epilogue.
// xs is pre-scaled (dis*x). out_agg[i] = dis[i]*(sum_src xs[src] + xs[i]).
// MODE 0: o=relu(ln); 1: o+=0.7*prev(unscale); 2: o=0.7*o+prev(unscale).
// SOUT: store dis*o (for the next layer's gather source).
template<int MODE, int K, bool SOUT>
__global__ __launch_bounds__(512) void fused_k(
    const unsigned short* __restrict__ xs, const int* __restrict__ row_ptr,
    const int* __restrict__ srcs, const float* __restrict__ dis,
    const unsigned short* __restrict__ Wp,
    const float* __restrict__ bias, const float* __restrict__ gam,
    const float* __restrict__ bet, const unsigned short* __restrict__ xprev,
    unsigned short* __restrict__ out, int n) {
  constexpr int CN = 256, NSUB = 16, KC = K / 32;
  constexpr int STRIDE = K + 8;            // shorts; 528B/272B => free 2-way banks
  constexpr int LPR = K / 8;               // lanes per row (16B/lane)
  constexpr int RP = 64 / LPR;             // rows gathered in parallel per wave
  constexpr int NIT = 8 / RP;
  __shared__ unsigned short aggS[64 * STRIDE];
  __shared__ float red_s[64][4], red_q[64][4];

  const int t = threadIdx.x;
  const int w = t >> 6, lane = t & 63;
  const int m0 = blockIdx.x * 64;

  // ---------------- phase 1: gather ----------------
  {
    const int gi = lane / LPR, li = lane % LPR;
    const unsigned short* xb = xs + li * 8;
#pragma unroll
    for (int it = 0; it < NIT; ++it) {
      const int lr = w * 8 + it * RP + gi;
      const int tg = m0 + lr;
      const int tgc = tg < n ? tg : n - 1;
      const int beg = row_ptr[tgc], end = row_ptr[tgc + 1];
      const float di = dis[tgc];
      float acc[8];
      {
        uint4 v = *(const uint4*)(xb + (size_t)tgc * K);
        acc[0] = bf2f(v.x & 0xffffu); acc[1] = bf2f(v.x >> 16);
        acc[2] = bf2f(v.y & 0xffffu); acc[3] = bf2f(v.y >> 16);
        acc[4] = bf2f(v.z & 0xffffu); acc[5] = bf2f(v.z >> 16);
        acc[6] = bf2f(v.w & 0xffffu); acc[7] = bf2f(v.w >> 16);
      }
      int j = beg;
      for (; j + 16 <= end; j += 16) {
        int4 sA = *(const int4*)(srcs + j);
        int4 sB = *(const int4*)(srcs + j + 4);
        int4 sC = *(const int4*)(srcs + j + 8);
        int4 sD = *(const int4*)(srcs + j + 12);
        uint4 u0 = *(const uint4*)(xb + (size_t)sA.x * K);
        uint4 u1 = *(const uint4*)(xb + (size_t)sA.y * K);
        uint4 u2 = *(const uint4*)(xb + (size_t)sA.z * K);
        uint4 u3 = *(const uint4*)(xb + (size_t)sA.w * K);
        uint4 u4 = *(const uint4*)(xb + (size_t)sB.x * K);
        uint4 u5 = *(const uint4*)(xb + (size_t)sB.y * K);
        uint4 u6 = *(const uint4*)(xb + (size_t)sB.z * K);
        uint4 u7 = *(const uint4*)(xb + (size_t)sB.w * K);
        uint4 u8 = *(const uint4*)(xb + (size_t)sC.x * K);
        uint4 u9 = *(const uint4*)(xb + (size_t)sC.y * K);
        uint4 uA = *(const uint4*)(xb + (size_t)sC.z * K);
        uint4 uB = *(const uint4*)(xb + (size_t)sC.w * K);
        uint4 uC = *(const uint4*)(xb + (size_t)sD.x * K);
        uint4 uD = *(const uint4*)(xb + (size_t)sD.y * K);
        uint4 uE = *(const uint4*)(xb + (size_t)sD.z * K);
        uint4 uF = *(const uint4*)(xb + (size_t)sD.w * K);
        ACC8(u0); ACC8(u1); ACC8(u2); ACC8(u3);
        ACC8(u4); ACC8(u5); ACC8(u6); ACC8(u7);
        ACC8(u8); ACC8(u9); ACC8(uA); ACC8(uB);
        ACC8(uC); ACC8(uD); ACC8(uE); ACC8(uF);
      }
      for (; j + 4 <= end; j += 4) {
        int4 sA = *(const int4*)(srcs + j);
        uint4 u0 = *(const uint4*)(xb + (size_t)sA.x * K);
        uint4 u1 = *(const uint4*)(xb + (size_t)sA.y * K);
        uint4 u2 = *(const uint4*)(xb + (size_t)sA.z * K);
        uint4 u3 = *(const uint4*)(xb + (size_t)sA.w * K);
        ACC8(u0); ACC8(u1); ACC8(u2); ACC8(u3);
      }
      for (; j < end; ++j) {
        uint4 u = *(const uint4*)(xb + (size_t)srcs[j] * K);
        ACC8(u);
      }
      uint4 o;
      o.x = (unsigned int)f2bf(di * acc[0]) | ((unsigned int)f2bf(di * acc[1]) << 16);
      o.y = (unsigned int)f2bf(di * acc[2]) | ((unsigned int)f2bf(di * acc[3]) << 16);
      o.z = (unsigned int)f2bf(di * acc[4]) | ((unsigned int)f2bf(di * acc[5]) << 16);
      o.w = (unsigned int)f2bf(di * acc[6]) | ((unsigned int)f2bf(di * acc[7]) << 16);
      *(uint4*)&aggS[lr * STRIDE + li * 8] = o;
    }
  }
  __syncthreads();

  // ---------------- phase 2: GEMM + LN ----------------
  const int rg = w & 1, cg = w >> 1;
  const int gq = lane >> 4, i = lane & 15;
  const unsigned short* aL0 = &aggS[(rg * 32 + i) * STRIDE + gq * 8];
  const unsigned short* aL1 = aL0 + 16 * STRIDE;
  const short8* wp = (const short8*)Wp + (size_t)(cg * 4) * 64 + lane;

  f32x4 acc[2][4];
#pragma unroll
  for (int rr = 0; rr < 2; ++rr)
#pragma unroll
    for (int j = 0; j < 4; ++j) acc[rr][j] = (f32x4){0.f, 0.f, 0.f, 0.f};

  short8 wf[4];
#pragma unroll
  for (int j = 0; j < 4; ++j) wf[j] = wp[j * 64];

#pragma unroll
  for (int kc = 0; kc < KC; ++kc) {
    short8 nwf[4];
    if (kc + 1 < KC) {
#pragma unroll
      for (int j = 0; j < 4; ++j) nwf[j] = wp[(size_t)(kc + 1) * NSUB * 64 + j * 64];
    }
    short8 af0 = *(const short8*)(aL0 + kc * 32);
    short8 af1 = *(const short8*)(aL1 + kc * 32);
#pragma unroll
    for (int j = 0; j < 4; ++j) {
      acc[0][j] = __builtin_amdgcn_mfma_f32_16x16x32_bf16(wf[j], af0, acc[0][j], 0, 0, 0);
      acc[1][j] = __builtin_amdgcn_mfma_f32_16x16x32_bf16(wf[j], af1, acc[1][j], 0, 0, 0);
    }
    if (kc + 1 < KC) {
#pragma unroll
      for (int j = 0; j < 4; ++j) wf[j] = nwf[j];
    }
  }

  const int colb = cg * 64 + gq * 4;
  float s0 = 0.f, q0 = 0.f, s1 = 0.f, q1 = 0.f;
#pragma unroll
  for (int j = 0; j < 4; ++j) {
    f32x4 b4 = *(const f32x4*)(bias + colb + j * 16);
#pragma unroll
    for (int r = 0; r < 4; ++r) {
      acc[0][j][r] += b4[r];
      acc[1][j][r] += b4[r];
      float v = acc[0][j][r]; s0 += v; q0 += v * v;
      float u = acc[1][j][r]; s1 += u; q1 += u * u;
    }
  }
  s0 += __shfl_xor(s0, 16); s0 += __shfl_xor(s0, 32);
  q0 += __shfl_xor(q0, 16); q0 += __shfl_xor(q0, 32);
  s1 += __shfl_xor(s1, 16); s1 += __shfl_xor(s1, 32);
  q1 += __shfl_xor(q1, 16); q1 += __shfl_xor(q1, 32);
  if (gq == 0) {
    red_s[rg * 32 + i][cg] = s0;      red_q[rg * 32 + i][cg] = q0;
    red_s[rg * 32 + 16 + i][cg] = s1; red_q[rg * 32 + 16 + i][cg] = q1;
  }
  __syncthreads();

#pragma unroll
  for (int rr = 0; rr < 2; ++rr) {
    int il = rg * 32 + rr * 16 + i;
    int r = m0 + il;
    if (r >= n) continue;
    float ss = (red_s[il][0] + red_s[il][1]) + (red_s[il][2] + red_s[il][3]);
    float qq = (red_q[il][0] + red_q[il][1]) + (red_q[il][2] + red_q[il][3]);
    float mu = ss * (1.f / CN);
    float inv = rsqrtf(qq * (1.f / CN) - mu * mu + EPSV);
    float di = dis[r];
    float rinv = (MODE != 0) ? 1.0f / di : 0.f;
    unsigned short* op = out + (size_t)r * CN + colb;
    const unsigned short* pp = (MODE != 0) ? (xprev + (size_t)r * CN + colb) : nullptr;
#pragma unroll
    for (int j = 0; j < 4; ++j) {
      f32x4 g4 = *(const f32x4*)(gam + colb + j * 16);
      f32x4 e4 = *(const f32x4*)(bet + colb + j * 16);
      float o0 = fmaxf((acc[rr][j][0] - mu) * inv * g4[0] + e4[0], 0.f);
      float o1 = fmaxf((acc[rr][j][1] - mu) * inv * g4[1] + e4[1], 0.f);
      float o2 = fmaxf((acc[rr][j][2] - mu) * inv * g4[2] + e4[2], 0.f);
      float o3 = fmaxf((acc[rr][j][3] - mu) * inv * g4[3] + e4[3], 0.f);
      if (MODE == 1) {
        float4 pv = ldbf4(pp + j * 16);
        o0 += 0.7f * rinv * pv.x; o1 += 0.7f * rinv * pv.y;
        o2 += 0.7f * rinv * pv.z; o3 += 0.7f * rinv * pv.w;
      } else if (MODE == 2) {
        float4 pv = ldbf4(pp + j * 16);
        o0 = o0 * 0.7f + rinv * pv.x; o1 = o1 * 0.7f + rinv * pv.y;
        o2 = o2 * 0.7f + rinv * pv.z; o3 = o3 * 0.7f + rinv * pv.w;
      }
      if (SOUT) { o0 *= di; o1 *= di; o2 *= di; o3 *= di; }
      stbf4(op + j * 16, o0, o1, o2, o3);
    }
  }
}

// ---------------- fused MLP head: out[i] = relu(x3@Wf1+bf1) @ Wf2 + bf2 --------
__global__ __launch_bounds__(256) void gemmdot_k(
    const unsigned short* __restrict__ A, const unsigned short* __restrict__ Wp,
    const float* __restrict__ b1, const float* __restrict__ w2,
    const float* __restrict__ b2, float* __restrict__ out, int n) {
  constexpr int K = 256, NSUB = 8, KC = 8;
  __shared__ float redh[64][2];
  const int t = threadIdx.x;
  const int w = t >> 6, lane = t & 63;
  const int rg = w & 1, cg = w >> 1;
  const int gq = lane >> 4, i = lane & 15;
  const int m0 = blockIdx.x * 64;
  const int r0 = m0 + rg * 32 + i, r1 = r0 + 16;
  const int l0 = r0 < n ? r0 : n - 1, l1 = r1 < n ? r1 : n - 1;
  const unsigned short* a0 = A + (size_t)l0 * K + gq * 8;
  const unsigned short* a1 = A + (size_t)l1 * K + gq * 8;
  const short8* wp = (const short8*)Wp + (size_t)(cg * 4) * 64 + lane;

  f32x4 acc[2][4];
#pragma unroll
  for (int rr = 0; rr < 2; ++rr)
#pragma unroll
    for (int j = 0; j < 4; ++j) acc[rr][j] = (f32x4){0.f, 0.f, 0.f, 0.f};

  short8 af0 = *(const short8*)a0;
  short8 af1 = *(const short8*)a1;
  short8 wf[4];
#pragma unroll
  for (int j = 0; j < 4; ++j) wf[j] = wp[j * 64];

#pragma unroll
  for (int kc = 0; kc < KC; ++kc) {
    short8 naf0, naf1, nwf[4];
    if (kc + 1 < KC) {
      naf0 = *(const short8*)(a0 + (kc + 1) * 32);
      naf1 = *(const short8*)(a1 + (kc + 1) * 32);
#pragma unroll
      for (int j = 0; j < 4; ++j) nwf[j] = wp[(size_t)(kc + 1) * NSUB * 64 + j * 64];
    }
#pragma unroll
    for (int j = 0; j < 4; ++j) {
      acc[0][j] = __builtin_amdgcn_mfma_f32_16x16x32_bf16(wf[j], af0, acc[0][j], 0, 0, 0);
      acc[1][j] = __builtin_amdgcn_mfma_f32_16x16x32_bf16(wf[j], af1, acc[1][j], 0, 0, 0);
    }
    if (kc + 1 < KC) {
      af0 = naf0; af1 = naf1;
#pragma unroll
      for (int j = 0; j < 4; ++j) wf[j] = nwf[j];
    }
  }

  const int colb = cg * 64 + gq * 4;
  float p0 = 0.f, p1 = 0.f;
#pragma unroll
  for (int j = 0; j < 4; ++j) {
    f32x4 bb = *(const f32x4*)(b1 + colb + j * 16);
    f32x4 ww = *(const f32x4*)(w2 + colb + j * 16);
#pragma unroll
    for (int r = 0; r < 4; ++r) {
      p0 += fmaxf(acc[0][j][r] + bb[r], 0.f) * ww[r];
      p1 += fmaxf(acc[1][j][r] + bb[r], 0.f) * ww[r];
    }
  }
  p0 += __shfl_xor(p0, 16); p0 += __shfl_xor(p0, 32);
  p1 += __shfl_xor(p1, 16); p1 += __shfl_xor(p1, 32);
  if (gq == 0) {
    redh[rg * 32 + i][cg] = p0;
    redh[rg * 32 + 16 + i][cg] = p1;
  }
  __syncthreads();
  if (t < 64) {
    int r = m0 + t;
    if (r < n) out[r] = redh[t][0] + redh[t][1] + b2[0];
  }
}

extern "C" void kernel_launch(void* const* d_in, const int* in_sizes, int n_in,
                              void* d_out, int out_size, void* d_ws, size_t ws_size,
                              hipStream_t stream) {
  const float* x   = (const float*)d_in[0];
  const int*   ei  = (const int*)d_in[1];
  const float* W1  = (const float*)d_in[2];
  const float* b1  = (const float*)d_in[3];
  const float* g1  = (const float*)d_in[4];
  const float* be1 = (const float*)d_in[5];
  const float* W2  = (const float*)d_in[6];
  const float* b2  = (const float*)d_in[7];
  const float* g2  = (const float*)d_in[8];
  const float* be2 = (const float*)d_in[9];
  const float* W3  = (const float*)d_in[10];
  const float* b3  = (const float*)d_in[11];
  const float* g3  = (const float*)d_in[12];
  const float* be3 = (const float*)d_in[13];
  const float* Wf1 = (const float*)d_in[14];
  const float* bf1 = (const float*)d_in[15];
  const float* Wf2 = (const float*)d_in[16];
  const float* bf2 = (const float*)d_in[17];
  float* out = (float*)d_out;

  const int n = in_sizes[0] / DIN;   // 50000
  const int e = in_sizes[1] / 2;     // 800000
  const int* row = ei;               // sources
  const int* col = ei + e;           // targets

  char* ws = (char*)d_ws;
  size_t off = 0;
  auto alloc = [&](size_t bytes) -> void* {
    void* p = ws + off;
    off = (off + bytes + 255) & ~(size_t)255;
    return p;
  };
  float*          dis     = (float*)alloc((size_t)n * 4);
  int*            deg_i   = (int*)alloc((size_t)n * 4);
  int*            cur     = (int*)alloc((size_t)n * 4);
  int*            row_ptr = (int*)alloc((size_t)(n + 1) * 4);
  int*            bsums   = (int*)alloc((size_t)256 * 4);
  int*            srcs    = (int*)alloc((size_t)e * 4);
  unsigned short* W1p     = (unsigned short*)alloc((size_t)DIN * HDIM * 2);
  unsigned short* W2p     = (unsigned short*)alloc((size_t)HDIM * HDIM * 2);
  unsigned short* W3p     = (unsigned short*)alloc((size_t)HDIM * HDIM * 2);
  unsigned short* Wf1p    = (unsigned short*)alloc((size_t)HDIM * 128 * 2);
  unsigned short* xsb     = (unsigned short*)alloc((size_t)n * DIN * 2);   // dis*x
  unsigned short* x1s     = (unsigned short*)alloc((size_t)n * HDIM * 2);  // dis*x1
  unsigned short* x2s     = (unsigned short*)alloc((size_t)n * HDIM * 2);  // dis*x2
  unsigned short* x3      = (unsigned short*)alloc((size_t)n * HDIM * 2);  // x3

  const int eb  = (e + 255) / 256;
  const int gb  = (n + 63) / 64;
  const int sb_ = (n + SCHUNK - 1) / SCHUNK;
  const int prep_tot = DIN * HDIM + HDIM * HDIM + HDIM * HDIM + HDIM * 128 + n * DIN;

  // CSR build + normalization
  hipMemsetAsync(deg_i, 0, ((char*)row_ptr - (char*)deg_i), stream);  // deg + cur
  hist_k<<<eb, 256, 0, stream>>>(col, deg_i, e);
  scanA_k<<<sb_, 256, 0, stream>>>(deg_i, row_ptr, bsums, dis, n);
  scanC_k<<<sb_, 256, 0, stream>>>(row_ptr, bsums, n, e, sb_);
  fill_k<<<eb, 256, 0, stream>>>(row, col, row_ptr, cur, srcs, e);

  // weight packs + scaled input cast
  prep_k<<<(prep_tot + 255) / 256, 256, 0, stream>>>(W1, W2, W3, Wf1, x, dis,
                                                     W1p, W2p, W3p, Wf1p, xsb, n * DIN);

  // layer 1: fused gather(128) + GEMM + LN -> x1s (scaled)
  fused_k<0, DIN, true><<<gb, 512, 0, stream>>>(
      xsb, row_ptr, srcs, dis, W1p, b1, g1, be1, nullptr, x1s, n);

  // layer 2: fused gather(256) + GEMM + LN + residual -> x2s (scaled)
  fused_k<1, HDIM, true><<<gb, 512, 0, stream>>>(
      x1s, row_ptr, srcs, dis, W2p, b2, g2, be2, x1s, x2s, n);

  // layer 3: fused gather(256) + GEMM + LN + residual -> x3 (unscaled)
  fused_k<2, HDIM, false><<<gb, 512, 0, stream>>>(
      x2s, row_ptr, srcs, dis, W3p, b3, g3, be3, x2s, x3, n);

  // fused MLP head
  gemmdot_k<<<gb, 256, 0, stream>>>(x3, Wf1p, bf1, Wf2, bf2, out, n);
}

// Round 10
// 425.040 us; speedup vs baseline: 1.1301x; 1.1301x over previous
//
#include <hip/hip_runtime.h>
#include <cstdint>
#include <cstddef>

#define HDIM 256
#define DIN 128
#define EPSV 1e-5f
#define SCHUNK 1024

typedef __attribute__((ext_vector_type(8))) short short8;   // 8 bf16 = 4 VGPRs
typedef __attribute__((ext_vector_type(4))) float f32x4;    // MFMA acc

__device__ __forceinline__ float bf2f(unsigned int u16) {
  union { unsigned int i; float f; } v; v.i = u16 << 16; return v.f;
}
__device__ __forceinline__ unsigned short f2bf(float f) {
  union { float f; unsigned int i; } v; v.f = f;
  unsigned int u = v.i;
  return (unsigned short)((u + 0x7fffu + ((u >> 16) & 1u)) >> 16);
}
__device__ __forceinline__ float4 ldbf4(const unsigned short* p) {
  uint2 v = *(const uint2*)p;
  return make_float4(bf2f(v.x & 0xffffu), bf2f(v.x >> 16),
                     bf2f(v.y & 0xffffu), bf2f(v.y >> 16));
}
__device__ __forceinline__ void stbf4(unsigned short* p, float a, float b, float c, float d) {
  uint2 o;
  o.x = (unsigned int)f2bf(a) | ((unsigned int)f2bf(b) << 16);
  o.y = (unsigned int)f2bf(c) | ((unsigned int)f2bf(d) << 16);
  *(uint2*)p = o;
}
#define ACC8(u) do { \
    acc[0] += bf2f((u).x & 0xffffu); acc[1] += bf2f((u).x >> 16); \
    acc[2] += bf2f((u).y & 0xffffu); acc[3] += bf2f((u).y >> 16); \
    acc[4] += bf2f((u).z & 0xffffu); acc[5] += bf2f((u).z >> 16); \
    acc[6] += bf2f((u).w & 0xffffu); acc[7] += bf2f((u).w >> 16); } while (0)

// ---------------- CSR build ----------------
// hist also records each edge's arrival rank -> fill needs no atomics
__global__ __launch_bounds__(256) void hist_k(const int* __restrict__ col,
                                              int* deg, int* __restrict__ rank, int e) {
  int i = blockIdx.x * 256 + threadIdx.x;
  if (i < e) rank[i] = atomicAdd(&deg[col[i]], 1);
}

__global__ __launch_bounds__(256) void scanA_k(const int* __restrict__ deg,
                                               int* __restrict__ row_ptr,
                                               int* __restrict__ blockSums,
                                               float* __restrict__ dis, int n) {
  __shared__ int waveSums[4];
  const int tid = threadIdx.x, lane = tid & 63, w = tid >> 6;
  const int base = blockIdx.x * SCHUNK + tid * 4;
  int v0 = 0, v1 = 0, v2 = 0, v3 = 0;
  if (base + 0 < n) v0 = deg[base + 0];
  if (base + 1 < n) v1 = deg[base + 1];
  if (base + 2 < n) v2 = deg[base + 2];
  if (base + 3 < n) v3 = deg[base + 3];
  if (base + 0 < n) dis[base + 0] = rsqrtf((float)(v0 + 1));
  if (base + 1 < n) dis[base + 1] = rsqrtf((float)(v1 + 1));
  if (base + 2 < n) dis[base + 2] = rsqrtf((float)(v2 + 1));
  if (base + 3 < n) dis[base + 3] = rsqrtf((float)(v3 + 1));
  int tsum = v0 + v1 + v2 + v3;
  int inc = tsum;
#pragma unroll
  for (int off = 1; off < 64; off <<= 1) {
    int t = __shfl_up(inc, off);
    if (lane >= off) inc += t;
  }
  if (lane == 63) waveSums[w] = inc;
  __syncthreads();
  int woff = 0;
#pragma unroll
  for (int k = 0; k < 4; ++k) woff += (k < w) ? waveSums[k] : 0;
  int excl = woff + inc - tsum;
  if (base + 0 < n) row_ptr[base + 0] = excl;
  if (base + 1 < n) row_ptr[base + 1] = excl + v0;
  if (base + 2 < n) row_ptr[base + 2] = excl + v0 + v1;
  if (base + 3 < n) row_ptr[base + 3] = excl + v0 + v1 + v2;
  if (tid == 255) blockSums[blockIdx.x] = woff + inc;
}

// scanC: per-block computes its prefix over <=64 block sums, adds to row_ptr
__global__ __launch_bounds__(256) void scanC_k(int* __restrict__ row_ptr,
                                               const int* __restrict__ bsums,
                                               int n, int e, int nbs) {
  __shared__ int s_add;
  if (threadIdx.x < 64) {
    int v = (threadIdx.x < nbs && threadIdx.x < blockIdx.x) ? bsums[threadIdx.x] : 0;
#pragma unroll
    for (int off = 1; off < 64; off <<= 1) v += __shfl_xor(v, off);
    if (threadIdx.x == 0) s_add = v;
  }
  __syncthreads();
  const int add = s_add;
  const int base = blockIdx.x * SCHUNK + threadIdx.x * 4;
#pragma unroll
  for (int k = 0; k < 4; ++k)
    if (base + k < n) row_ptr[base + k] += add;
  if (blockIdx.x == 0 && threadIdx.x == 0) row_ptr[n] = e;
}

__global__ __launch_bounds__(256) void fill_k(const int* __restrict__ row,
                                              const int* __restrict__ col,
                                              const int* __restrict__ row_ptr,
                                              const int* __restrict__ rank,
                                              int* __restrict__ srcs, int e) {
  int i = blockIdx.x * 256 + threadIdx.x;
  if (i < e) srcs[row_ptr[col[i]] + rank[i]] = row[i];
}

// ---------------- prep: pack 4 weights + cast scaled x ----------------
__device__ __forceinline__ void packW(const float* __restrict__ W,
                                      unsigned short* __restrict__ out,
                                      int idx, int C) {
  int j = idx & 7, lane = (idx >> 3) & 63, rest = idx >> 9;
  int NSUB = C >> 4;
  int ns = rest % NSUB, kb = rest / NSUB;
  int k = kb * 32 + (lane >> 4) * 8 + j;
  int c = ns * 16 + (lane & 15);
  out[idx] = f2bf(W[(size_t)k * C + c]);
}

__global__ __launch_bounds__(256) void prep_k(
    const float* __restrict__ W1, const float* __restrict__ W2,
    const float* __restrict__ W3, const float* __restrict__ Wf1,
    const float* __restrict__ x, const float* __restrict__ dis,
    unsigned short* __restrict__ W1p, unsigned short* __restrict__ W2p,
    unsigned short* __restrict__ W3p, unsigned short* __restrict__ Wf1p,
    unsigned short* __restrict__ xs, int nx) {
  int idx = blockIdx.x * 256 + threadIdx.x;
  const int s0 = DIN * HDIM, s1 = s0 + HDIM * HDIM, s2 = s1 + HDIM * HDIM,
            s3 = s2 + HDIM * 128;
  if (idx < s0) packW(W1, W1p, idx, HDIM);
  else if (idx < s1) packW(W2, W2p, idx - s0, HDIM);
  else if (idx < s2) packW(W3, W3p, idx - s1, HDIM);
  else if (idx < s3) packW(Wf1, Wf1p, idx - s2, 128);
  else {
    int o = idx - s3;
    if (o < nx) xs[o] = f2bf(x[o] * dis[o >> 7]);   // row = o/128
  }
}

// ------- gather256: out[i] = dis[i]*(sum xs[s] + xs[i]); xs pre-scaled by dis ---
// 2 target rows/wave (32 lanes x 16B); 16-deep load pipeline.
__global__ __launch_bounds__(256) void gather256_k(
    const unsigned short* __restrict__ xs, const int* __restrict__ row_ptr,
    const int* __restrict__ srcs, const float* __restrict__ dis,
    unsigned short* __restrict__ out, int n) {
  int wv = blockIdx.x * 4 + (threadIdx.x >> 6);
  int lane = threadIdx.x & 63;
  int half = lane >> 5, li = lane & 31;
  int i = wv * 2 + half;
  bool valid = i < n;
  int ic = valid ? i : n - 1;
  int beg = row_ptr[ic], end = row_ptr[ic + 1];
  float di = dis[ic];
  const int co = li * 8;
  const unsigned short* xb = xs + co;
  float acc[8];
  {
    uint4 v = *(const uint4*)(xb + (size_t)ic * 256);
    acc[0] = bf2f(v.x & 0xffffu); acc[1] = bf2f(v.x >> 16);
    acc[2] = bf2f(v.y & 0xffffu); acc[3] = bf2f(v.y >> 16);
    acc[4] = bf2f(v.z & 0xffffu); acc[5] = bf2f(v.z >> 16);
    acc[6] = bf2f(v.w & 0xffffu); acc[7] = bf2f(v.w >> 16);
  }
  int j = beg;
  for (; j + 16 <= end; j += 16) {
    int4 sA = *(const int4*)(srcs + j);
    int4 sB = *(const int4*)(srcs + j + 4);
    int4 sC = *(const int4*)(srcs + j + 8);
    int4 sD = *(const int4*)(srcs + j + 12);
    uint4 u0 = *(const uint4*)(xb + (size_t)sA.x * 256);
    uint4 u1 = *(const uint4*)(xb + (size_t)sA.y * 256);
    uint4 u2 = *(const uint4*)(xb + (size_t)sA.z * 256);
    uint4 u3 = *(const uint4*)(xb + (size_t)sA.w * 256);
    uint4 u4 = *(const uint4*)(xb + (size_t)sB.x * 256);
    uint4 u5 = *(const uint4*)(xb + (size_t)sB.y * 256);
    uint4 u6 = *(const uint4*)(xb + (size_t)sB.z * 256);
    uint4 u7 = *(const uint4*)(xb + (size_t)sB.w * 256);
    uint4 u8 = *(const uint4*)(xb + (size_t)sC.x * 256);
    uint4 u9 = *(const uint4*)(xb + (size_t)sC.y * 256);
    uint4 uA = *(const uint4*)(xb + (size_t)sC.z * 256);
    uint4 uB = *(const uint4*)(xb + (size_t)sC.w * 256);
    uint4 uC = *(const uint4*)(xb + (size_t)sD.x * 256);
    uint4 uD = *(const uint4*)(xb + (size_t)sD.y * 256);
    uint4 uE = *(const uint4*)(xb + (size_t)sD.z * 256);
    uint4 uF = *(const uint4*)(xb + (size_t)sD.w * 256);
    ACC8(u0); ACC8(u1); ACC8(u2); ACC8(u3);
    ACC8(u4); ACC8(u5); ACC8(u6); ACC8(u7);
    ACC8(u8); ACC8(u9); ACC8(uA); ACC8(uB);
    ACC8(uC); ACC8(uD); ACC8(uE); ACC8(uF);
  }
  for (; j + 4 <= end; j += 4) {
    int4 sA = *(const int4*)(srcs + j);
    uint4 u0 = *(const uint4*)(xb + (size_t)sA.x * 256);
    uint4 u1 = *(const uint4*)(xb + (size_t)sA.y * 256);
    uint4 u2 = *(const uint4*)(xb + (size_t)sA.z * 256);
    uint4 u3 = *(const uint4*)(xb + (size_t)sA.w * 256);
    ACC8(u0); ACC8(u1); ACC8(u2); ACC8(u3);
  }
  for (; j < end; ++j) {
    uint4 u = *(const uint4*)(xb + (size_t)srcs[j] * 256);
    ACC8(u);
  }
  if (valid) {
    uint4 o;
    o.x = (unsigned int)f2bf(di * acc[0]) | ((unsigned int)f2bf(di * acc[1]) << 16);
    o.y = (unsigned int)f2bf(di * acc[2]) | ((unsigned int)f2bf(di * acc[3]) << 16);
    o.z = (unsigned int)f2bf(di * acc[4]) | ((unsigned int)f2bf(di * acc[5]) << 16);
    o.w = (unsigned int)f2bf(di * acc[6]) | ((unsigned int)f2bf(di * acc[7]) << 16);
    *(uint4*)(out + (size_t)i * 256 + co) = o;
  }
}

// ------- gather128: 4 target rows/wave (16 lanes x 16B); 16-deep pipeline ------
__global__ __launch_bounds__(256) void gather128_k(
    const unsigned short* __restrict__ xs, const int* __restrict__ row_ptr,
    const int* __restrict__ srcs, const float* __restrict__ dis,
    unsigned short* __restrict__ out, int n) {
  int wv = blockIdx.x * 4 + (threadIdx.x >> 6);
  int lane = threadIdx.x & 63;
  int q = lane >> 4, li = lane & 15;
  int i = wv * 4 + q;
  bool valid = i < n;
  int ic = valid ? i : n - 1;
  int beg = row_ptr[ic], end = row_ptr[ic + 1];
  float di = dis[ic];
  const int co = li * 8;
  const unsigned short* xb = xs + co;
  float acc[8];
  {
    uint4 v = *(const uint4*)(xb + (size_t)ic * 128);
    acc[0] = bf2f(v.x & 0xffffu); acc[1] = bf2f(v.x >> 16);
    acc[2] = bf2f(v.y & 0xffffu); acc[3] = bf2f(v.y >> 16);
    acc[4] = bf2f(v.z & 0xffffu); acc[5] = bf2f(v.z >> 16);
    acc[6] = bf2f(v.w & 0xffffu); acc[7] = bf2f(v.w >> 16);
  }
  int j = beg;
  for (; j + 16 <= end; j += 16) {
    int4 sA = *(const int4*)(srcs + j);
    int4 sB = *(const int4*)(srcs + j + 4);
    int4 sC = *(const int4*)(srcs + j + 8);
    int4 sD = *(const int4*)(srcs + j + 12);
    uint4 u0 = *(const uint4*)(xb + (size_t)sA.x * 128);
    uint4 u1 = *(const uint4*)(xb + (size_t)sA.y * 128);
    uint4 u2 = *(const uint4*)(xb + (size_t)sA.z * 128);
    uint4 u3 = *(const uint4*)(xb + (size_t)sA.w * 128);
    uint4 u4 = *(const uint4*)(xb + (size_t)sB.x * 128);
    uint4 u5 = *(const uint4*)(xb + (size_t)sB.y * 128);
    uint4 u6 = *(const uint4*)(xb + (size_t)sB.z * 128);
    uint4 u7 = *(const uint4*)(xb + (size_t)sB.w * 128);
    uint4 u8 = *(const uint4*)(xb + (size_t)sC.x * 128);
    uint4 u9 = *(const uint4*)(xb + (size_t)sC.y * 128);
    uint4 uA = *(const uint4*)(xb + (size_t)sC.z * 128);
    uint4 uB = *(const uint4*)(xb + (size_t)sC.w * 128);
    uint4 uC = *(const uint4*)(xb + (size_t)sD.x * 128);
    uint4 uD = *(const uint4*)(xb + (size_t)sD.y * 128);
    uint4 uE = *(const uint4*)(xb + (size_t)sD.z * 128);
    uint4 uF = *(const uint4*)(xb + (size_t)sD.w * 128);
    ACC8(u0); ACC8(u1); ACC8(u2); ACC8(u3);
    ACC8(u4); ACC8(u5); ACC8(u6); ACC8(u7);
    ACC8(u8); ACC8(u9); ACC8(uA); ACC8(uB);
    ACC8(uC); ACC8(uD); ACC8(uE); ACC8(uF);
  }
  for (; j + 4 <= end; j += 4) {
    int4 sA = *(const int4*)(srcs + j);
    uint4 u0 = *(const uint4*)(xb + (size_t)sA.x * 128);
    uint4 u1 = *(const uint4*)(xb + (size_t)sA.y * 128);
    uint4 u2 = *(const uint4*)(xb + (size_t)sA.z * 128);
    uint4 u3 = *(const uint4*)(xb + (size_t)sA.w * 128);
    ACC8(u0); ACC8(u1); ACC8(u2); ACC8(u3);
  }
  for (; j < end; ++j) {
    uint4 u = *(const uint4*)(xb + (size_t)srcs[j] * 128);
    ACC8(u);
  }
  if (valid) {
    uint4 o;
    o.x = (unsigned int)f2bf(di * acc[0]) | ((unsigned int)f2bf(di * acc[1]) << 16);
    o.y = (unsigned int)f2bf(di * acc[2]) | ((unsigned int)f2bf(di * acc[3]) << 16);
    o.z = (unsigned int)f2bf(di * acc[4]) | ((unsigned int)f2bf(di * acc[5]) << 16);
    o.w = (unsigned int)f2bf(di * acc[6]) | ((unsigned int)f2bf(di * acc[7]) << 16);
    *(uint4*)(out + (size_t)i * 128 + co) = o;
  }
}

// ---------------- GEMM + bias + LN + ReLU + residual, 128-row blocks ----------
// 512 threads = 8 waves; wave = 32 rows x 128 cols (rg=w&3, cg=w>>2).
// block = 128 rows x 256 cols -> 2x weight-load amortization vs 64-row blocks.
// MODE 0: o=relu(ln); 1: o+=0.7*prev/dis; 2: o=0.7*o+prev/dis. SOUT: store dis*o.
template<int MODE, int K, bool SOUT>
__global__ __launch_bounds__(512) void gemmln_k(
    const unsigned short* __restrict__ A, const unsigned short* __restrict__ Wp,
    const float* __restrict__ bias, const float* __restrict__ gam,
    const float* __restrict__ bet, const unsigned short* __restrict__ xprev,
    const float* __restrict__ dis, unsigned short* __restrict__ out, int n) {
  constexpr int CN = 256, NSUBT = 16, KC = K / 32;
  __shared__ float red_s[128][2], red_q[128][2];
  const int t = threadIdx.x;
  const int w = t >> 6, lane = t & 63;
  const int rg = w & 3, cg = w >> 2;
  const int gq = lane >> 4, i = lane & 15;
  const int m0 = blockIdx.x * 128;
  const int r0 = m0 + rg * 32 + i, r1 = r0 + 16;
  const int l0 = r0 < n ? r0 : n - 1, l1 = r1 < n ? r1 : n - 1;
  const unsigned short* a0 = A + (size_t)l0 * K + gq * 8;
  const unsigned short* a1 = A + (size_t)l1 * K + gq * 8;
  const short8* wp = (const short8*)Wp + (size_t)(cg * 8) * 64 + lane;

  f32x4 acc[2][8];
#pragma unroll
  for (int rr = 0; rr < 2; ++rr)
#pragma unroll
    for (int j = 0; j < 8; ++j) acc[rr][j] = (f32x4){0.f, 0.f, 0.f, 0.f};

  short8 af0 = *(const short8*)a0;
  short8 af1 = *(const short8*)a1;
  short8 wf[8];
#pragma unroll
  for (int j = 0; j < 8; ++j) wf[j] = wp[j * 64];

#pragma unroll
  for (int kc = 0; kc < KC; ++kc) {
    short8 naf0, naf1, nwf[8];
    if (kc + 1 < KC) {
      naf0 = *(const short8*)(a0 + (kc + 1) * 32);
      naf1 = *(const short8*)(a1 + (kc + 1) * 32);
#pragma unroll
      for (int j = 0; j < 8; ++j) nwf[j] = wp[(size_t)(kc + 1) * NSUBT * 64 + j * 64];
    }
#pragma unroll
    for (int j = 0; j < 8; ++j) {
      acc[0][j] = __builtin_amdgcn_mfma_f32_16x16x32_bf16(wf[j], af0, acc[0][j], 0, 0, 0);
      acc[1][j] = __builtin_amdgcn_mfma_f32_16x16x32_bf16(wf[j], af1, acc[1][j], 0, 0, 0);
    }
    if (kc + 1 < KC) {
      af0 = naf0; af1 = naf1;
#pragma unroll
      for (int j = 0; j < 8; ++j) wf[j] = nwf[j];
    }
  }

  const int colb = cg * 128 + gq * 4;
  float s0 = 0.f, q0 = 0.f, s1 = 0.f, q1 = 0.f;
#pragma unroll
  for (int j = 0; j < 8; ++j) {
    f32x4 b4 = *(const f32x4*)(bias + colb + j * 16);
#pragma unroll
    for (int r = 0; r < 4; ++r) {
      acc[0][j][r] += b4[r];
      acc[1][j][r] += b4[r];
      float v = acc[0][j][r]; s0 += v; q0 += v * v;
      float u = acc[1][j][r]; s1 += u; q1 += u * u;
    }
  }
  s0 += __shfl_xor(s0, 16); s0 += __shfl_xor(s0, 32);
  q0 += __shfl_xor(q0, 16); q0 += __shfl_xor(q0, 32);
  s1 += __shfl_xor(s1, 16); s1 += __shfl_xor(s1, 32);
  q1 += __shfl_xor(q1, 16); q1 += __shfl_xor(q1, 32);
  if (gq == 0) {
    red_s[rg * 32 + i][cg] = s0;      red_q[rg * 32 + i][cg] = q0;
    red_s[rg * 32 + 16 + i][cg] = s1; red_q[rg * 32 + 16 + i][cg] = q1;
  }
  __syncthreads();

#pragma unroll
  for (int rr = 0; rr < 2; ++rr) {
    int il = rg * 32 + rr * 16 + i;
    int r = m0 + il;
    if (r >= n) continue;
    float ss = red_s[il][0] + red_s[il][1];
    float qq = red_q[il][0] + red_q[il][1];
    float mu = ss * (1.f / CN);
    float inv = rsqrtf(qq * (1.f / CN) - mu * mu + EPSV);
    float di = dis[r];
    float rinv = (MODE != 0) ? 1.0f / di : 0.f;
    unsigned short* op = out + (size_t)r * CN + colb;
    const unsigned short* pp = (MODE != 0) ? (xprev + (size_t)r * CN + colb) : nullptr;
#pragma unroll
    for (int j = 0; j < 8; ++j) {
      f32x4 g4 = *(const f32x4*)(gam + colb + j * 16);
      f32x4 e4 = *(const f32x4*)(bet + colb + j * 16);
      float o0 = fmaxf((acc[rr][j][0] - mu) * inv * g4[0] + e4[0], 0.f);
      float o1 = fmaxf((acc[rr][j][1] - mu) * inv * g4[1] + e4[1], 0.f);
      float o2 = fmaxf((acc[rr][j][2] - mu) * inv * g4[2] + e4[2], 0.f);
      float o3 = fmaxf((acc[rr][j][3] - mu) * inv * g4[3] + e4[3], 0.f);
      if (MODE == 1) {
        float4 pv = ldbf4(pp + j * 16);
        o0 += 0.7f * rinv * pv.x; o1 += 0.7f * rinv * pv.y;
        o2 += 0.7f * rinv * pv.z; o3 += 0.7f * rinv * pv.w;
      } else if (MODE == 2) {
        float4 pv = ldbf4(pp + j * 16);
        o0 = o0 * 0.7f + rinv * pv.x; o1 = o1 * 0.7f + rinv * pv.y;
        o2 = o2 * 0.7f + rinv * pv.z; o3 = o3 * 0.7f + rinv * pv.w;
      }
      if (SOUT) { o0 *= di; o1 *= di; o2 *= di; o3 *= di; }
      stbf4(op + j * 16, o0, o1, o2, o3);
    }
  }
}

// ---------------- fused MLP head, 128-row blocks ----------------
// 512 threads = 8 waves; wave = 32 rows x 64 cols (rg=w&3, cg=w>>2, cg<2).
// out[i] = relu(x3@Wf1+bf1) @ Wf2 + bf2
__global__ __launch_bounds__(512) void gemmdot_k(
    const unsigned short* __restrict__ A, const unsigned short* __restrict__ Wp,
    const float* __restrict__ b1, const float* __restrict__ w2,
    const float* __restrict__ b2, float* __restrict__ out, int n) {
  constexpr int K = 256, NSUBT = 8, KC = 8;
  __shared__ float redh[128][2];
  const int t = threadIdx.x;
  const int w = t >> 6, lane = t & 63;
  const int rg = w & 3, cg = w >> 2;
  const int gq = lane >> 4, i = lane & 15;
  const int m0 = blockIdx.x * 128;
  const int r0 = m0 + rg * 32 + i, r1 = r0 + 16;
  const int l0 = r0 < n ? r0 : n - 1, l1 = r1 < n ? r1 : n - 1;
  const unsigned short* a0 = A + (size_t)l0 * K + gq * 8;
  const unsigned short* a1 = A + (size_t)l1 * K + gq * 8;
  const short8* wp = (const short8*)Wp + (size_t)(cg * 4) * 64 + lane;

  f32x4 acc[2][4];
#pragma unroll
  for (int rr = 0; rr < 2; ++rr)
#pragma unroll
    for (int j = 0; j < 4; ++j) acc[rr][j] = (f32x4){0.f, 0.f, 0.f, 0.f};

  short8 af0 = *(const short8*)a0;
  short8 af1 = *(const short8*)a1;
  short8 wf[4];
#pragma unroll
  for (int j = 0; j < 4; ++j) wf[j] = wp[j * 64];

#pragma unroll
  for (int kc = 0; kc < KC; ++kc) {
    short8 naf0, naf1, nwf[4];
    if (kc + 1 < KC) {
      naf0 = *(const short8*)(a0 + (kc + 1) * 32);
      naf1 = *(const short8*)(a1 + (kc + 1) * 32);
#pragma unroll
      for (int j = 0; j < 4; ++j) nwf[j] = wp[(size_t)(kc + 1) * NSUBT * 64 + j * 64];
    }
#pragma unroll
    for (int j = 0; j < 4; ++j) {
      acc[0][j] = __builtin_amdgcn_mfma_f32_16x16x32_bf16(wf[j], af0, acc[0][j], 0, 0, 0);
      acc[1][j] = __builtin_amdgcn_mfma_f32_16x16x32_bf16(wf[j], af1, acc[1][j], 0, 0, 0);
    }
    if (kc + 1 < KC) {
      af0 = naf0; af1 = naf1;
#pragma unroll
      for (int j = 0; j < 4; ++j) wf[j] = nwf[j];
    }
  }

  const int colb = cg * 64 + gq * 4;
  float p0 = 0.f, p1 = 0.f;
#pragma unroll
  for (int j = 0; j < 4; ++j) {
    f32x4 bb = *(const f32x4*)(b1 + colb + j * 16);
    f32x4 ww = *(const f32x4*)(w2 + colb + j * 16);
#pragma unroll
    for (int r = 0; r < 4; ++r) {
      p0 += fmaxf(acc[0][j][r] + bb[r], 0.f) * ww[r];
      p1 += fmaxf(acc[1][j][r] + bb[r], 0.f) * ww[r];
    }
  }
  p0 += __shfl_xor(p0, 16); p0 += __shfl_xor(p0, 32);
  p1 += __shfl_xor(p1, 16); p1 += __shfl_xor(p1, 32);
  if (gq == 0) {
    redh[rg * 32 + i][cg] = p0;
    redh[rg * 32 + 16 + i][cg] = p1;
  }
  __syncthreads();
  if (t < 128) {
    int r = m0 + t;
    if (r < n) out[r] = redh[t][0] + redh[t][1] + b2[0];
  }
}

extern "C" void kernel_launch(void* const* d_in, const int* in_sizes, int n_in,
                              void* d_out, int out_size, void* d_ws, size_t ws_size,
                              hipStream_t stream) {
  const float* x   = (const float*)d_in[0];
  const int*   ei  = (const int*)d_in[1];
  const float* W1  = (const float*)d_in[2];
  const float* b1  = (const float*)d_in[3];
  const float* g1  = (const float*)d_in[4];
  const float* be1 = (const float*)d_in[5];
  const float* W2  = (const float*)d_in[6];
  const float* b2  = (const float*)d_in[7];
  const float* g2  = (const float*)d_in[8];
  const float* be2 = (const float*)d_in[9];
  const float* W3  = (const float*)d_in[10];
  const float* b3  = (const float*)d_in[11];
  const float* g3  = (const float*)d_in[12];
  const float* be3 = (const float*)d_in[13];
  const float* Wf1 = (const float*)d_in[14];
  const float* bf1 = (const float*)d_in[15];
  const float* Wf2 = (const float*)d_in[16];
  const float* bf2 = (const float*)d_in[17];
  float* out = (float*)d_out;

  const int n = in_sizes[0] / DIN;   // 50000
  const int e = in_sizes[1] / 2;     // 800000
  const int* row = ei;               // sources
  const int* col = ei + e;           // targets

  char* ws = (char*)d_ws;
  size_t off = 0;
  auto alloc = [&](size_t bytes) -> void* {
    void* p = ws + off;
    off = (off + bytes + 255) & ~(size_t)255;
    return p;
  };
  float*          dis     = (float*)alloc((size_t)n * 4);
  int*            deg_i   = (int*)alloc((size_t)n * 4);
  int*            row_ptr = (int*)alloc((size_t)(n + 1) * 4);
  int*            bsums   = (int*)alloc((size_t)256 * 4);
  int*            rank    = (int*)alloc((size_t)e * 4);
  int*            srcs    = (int*)alloc((size_t)e * 4);
  unsigned short* W1p     = (unsigned short*)alloc((size_t)DIN * HDIM * 2);
  unsigned short* W2p     = (unsigned short*)alloc((size_t)HDIM * HDIM * 2);
  unsigned short* W3p     = (unsigned short*)alloc((size_t)HDIM * HDIM * 2);
  unsigned short* Wf1p    = (unsigned short*)alloc((size_t)HDIM * 128 * 2);
  unsigned short* xsb     = (unsigned short*)alloc((size_t)n * DIN * 2);   // dis*x
  unsigned short* agg     = (unsigned short*)alloc((size_t)n * HDIM * 2);
  unsigned short* x1s     = (unsigned short*)alloc((size_t)n * HDIM * 2);  // dis*x1
  unsigned short* x2s     = (unsigned short*)alloc((size_t)n * HDIM * 2);  // dis*x2
  unsigned short* a1      = agg;   // layer-1 aggregate [n,128]
  unsigned short* x3      = x1s;   // x1s dead after gemmln<1> + gather(layer2)

  const int eb  = (e + 255) / 256;
  const int gb  = (n + 127) / 128;
  const int sb_ = (n + SCHUNK - 1) / SCHUNK;
  const int g2b = (n + 7) / 8;    // gather256: 8 targets/block
  const int g1b = (n + 15) / 16;  // gather128: 16 targets/block
  const int prep_tot = DIN * HDIM + HDIM * HDIM + HDIM * HDIM + HDIM * 128 + n * DIN;

  // CSR build + normalization (fill is atomic-free via rank)
  hipMemsetAsync(deg_i, 0, (size_t)n * 4, stream);
  hist_k<<<eb, 256, 0, stream>>>(col, deg_i, rank, e);
  scanA_k<<<sb_, 256, 0, stream>>>(deg_i, row_ptr, bsums, dis, n);
  scanC_k<<<sb_, 256, 0, stream>>>(row_ptr, bsums, n, e, sb_);
  fill_k<<<eb, 256, 0, stream>>>(row, col, row_ptr, rank, srcs, e);

  // weight packs + scaled input cast
  prep_k<<<(prep_tot + 255) / 256, 256, 0, stream>>>(W1, W2, W3, Wf1, x, dis,
                                                     W1p, W2p, W3p, Wf1p, xsb, n * DIN);

  // layer 1 -> x1s (scaled)
  gather128_k<<<g1b, 256, 0, stream>>>(xsb, row_ptr, srcs, dis, a1, n);
  gemmln_k<0, DIN, true><<<gb, 512, 0, stream>>>(a1, W1p, b1, g1, be1, nullptr, dis, x1s, n);

  // layer 2 -> x2s (scaled; residual reconstructs x1 = x1s/dis)
  gather256_k<<<g2b, 256, 0, stream>>>(x1s, row_ptr, srcs, dis, agg, n);
  gemmln_k<1, HDIM, true><<<gb, 512, 0, stream>>>(agg, W2p, b2, g2, be2, x1s, dis, x2s, n);

  // layer 3 -> x3 (unscaled; residual reconstructs x2 = x2s/dis)
  gather256_k<<<g2b, 256, 0, stream>>>(x2s, row_ptr, srcs, dis, agg, n);
  gemmln_k<2, HDIM, false><<<gb, 512, 0, stream>>>(agg, W3p, b3, g3, be3, x2s, dis, x3, n);

  // fused MLP head
  gemmdot_k<<<gb, 512, 0, stream>>>(x3, Wf1p, bf1, Wf2, bf2, out, n);
}